// Round 11
// baseline (690.213 us; speedup 1.0000x reference)
//
#include <hip/hip_runtime.h>

typedef float   f32x4 __attribute__((ext_vector_type(4)));
typedef _Float16 f16x8 __attribute__((ext_vector_type(8)));
typedef short   s16x8 __attribute__((ext_vector_type(8)));
typedef short   s16x4 __attribute__((ext_vector_type(4)));
typedef unsigned short u16;

#define NTOK 8192
#define CDIM 2048
#define NEXP 8
#define NASS 16384   // NTOK * TOP_K
#define MT   20      // 128-row m-tiles per expert: covers Me <= 2560 (+12 sigma)
#define ITEMS_PER_MODE (NEXP * MT * 8)      // 1280
#define EXPECTED_PER_E (MT * 8)             // 160

#define GLOBAL_AS __attribute__((address_space(1)))
#define LDS_AS    __attribute__((address_space(3)))

__device__ __forceinline__ u16 f2h_bits(float f) {
  _Float16 h = (_Float16)f;
  union { _Float16 h; u16 u; } v;
  v.h = h;
  return v.u;
}

// ---------- tiny: wr [C][E] f32 -> wrT [E][C] f32 ----------
__global__ __launch_bounds__(256) void moe_wrt(
    const float* __restrict__ wr, float* __restrict__ wrT)
{
  const int gid = blockIdx.x * 256 + threadIdx.x;   // 16384 elems
  const int c = gid >> 3, e = gid & 7;
  wrT[e * CDIM + c] = wr[c * NEXP + e];
}

// ---------- prep: router blocks (0..255) + transpose blocks (256..8447) ----------
// Independent DAG nodes co-scheduled in one launch: HBM-bound transpose fills
// the router's latency stalls.
__global__ __launch_bounds__(256) void moe_prep(
    const float* __restrict__ x, const float* __restrict__ wrT,
    u16* __restrict__ xh, int* __restrict__ top_idx,
    float* __restrict__ top_p, int* __restrict__ counts,
    const float* __restrict__ wfc, const float* __restrict__ wpj,
    u16* __restrict__ wfcT, u16* __restrict__ wpjT)
{
  __shared__ __attribute__((aligned(16))) char shm[64 * 129 * 4];
  const int id = blockIdx.x;
  if (id < 256) {
    // ---- router: 32 tokens per block, LDS count reduce ----
    int* scnt = (int*)shm;
    if (threadIdx.x < NEXP) scnt[threadIdx.x] = 0;
    __syncthreads();
    const int wave = threadIdx.x >> 6, lane = threadIdx.x & 63;
    for (int i = 0; i < 8; ++i) {
      const int n = id * 32 + i * 4 + wave;
      const float* xr = x + (size_t)n * CDIM;
      u16* xhr = xh + (size_t)n * CDIM;
      float acc[NEXP] = {};
      #pragma unroll
      for (int ii = 0; ii < CDIM / 256; ++ii) {
        const int c = ii * 256 + lane * 4;
        const f32x4 xv = *(const f32x4*)(xr + c);
        s16x4 hv;
        #pragma unroll
        for (int j = 0; j < 4; ++j) hv[j] = (short)f2h_bits(xv[j]);
        *(s16x4*)(xhr + c) = hv;                    // fused x -> f16
        #pragma unroll
        for (int e = 0; e < NEXP; ++e) {
          const f32x4 wv = *(const f32x4*)(wrT + (size_t)e * CDIM + c);
          acc[e] += xv[0]*wv[0] + xv[1]*wv[1] + xv[2]*wv[2] + xv[3]*wv[3];
        }
      }
      #pragma unroll
      for (int off = 32; off > 0; off >>= 1) {
        #pragma unroll
        for (int e = 0; e < NEXP; ++e) acc[e] += __shfl_xor(acc[e], off);
      }
      if (lane == 0) {
        int i0 = 0; float v0 = acc[0];
        #pragma unroll
        for (int e = 1; e < NEXP; ++e) { if (acc[e] > v0) { v0 = acc[e]; i0 = e; } }
        int i1 = -1; float v1 = -3.4e38f;
        #pragma unroll
        for (int e = 0; e < NEXP; ++e) { if (e != i0 && acc[e] > v1) { v1 = acc[e]; i1 = e; } }
        const float ex = __expf(v1 - v0);
        const float p0 = 1.f / (1.f + ex);
        top_idx[n * 2 + 0] = i0; top_idx[n * 2 + 1] = i1;
        top_p[n * 2 + 0] = p0;   top_p[n * 2 + 1] = 1.f - p0;
        atomicAdd(&scnt[i0], 1);
        atomicAdd(&scnt[i1], 1);
      }
    }
    __syncthreads();
    if (threadIdx.x < NEXP) atomicAdd(&counts[threadIdx.x], scnt[threadIdx.x]);
  } else {
    // ---- transpose: w [E][K][N] fp32 -> wT [E][N][K] f16, 64x128 tiles ----
    float (*lds)[129] = (float(*)[129])shm;
    const int tid2 = id - 256;                // 0..8191
    const int z  = tid2 >> 12;                // 0=fc, 1=pj
    const int r2 = tid2 & 4095;
    const int e  = r2 >> 9;
    const int xb = r2 & 511;
    const float* src = (z ? wpj : wfc) + (size_t)e * CDIM * CDIM;
    u16* dst = (z ? wpjT : wfcT) + (size_t)e * CDIM * CDIM;
    const int tr = (xb >> 4) * 64;
    const int tc = (xb & 15) * 128;
    const int t = threadIdx.x;
    #pragma unroll
    for (int p = 0; p < 8; ++p) {
      const int r  = p * 8 + (t >> 5);
      const int c4 = (t & 31) * 4;
      const f32x4 v = *(const f32x4*)(src + (size_t)(tr + r) * CDIM + tc + c4);
      #pragma unroll
      for (int j = 0; j < 4; ++j) lds[r][c4 + j] = v[j];
    }
    __syncthreads();
    const int d  = t >> 1;
    const int ks = (t & 1) * 32;
    u16* drow = dst + (size_t)(tc + d) * CDIM + tr + ks;
    #pragma unroll
    for (int q = 0; q < 4; ++q) {
      s16x8 o;
      #pragma unroll
      for (int j = 0; j < 8; ++j) o[j] = (short)f2h_bits(lds[ks + q * 8 + j][d]);
      *(s16x8*)(drow + q * 8) = o;
    }
  }
}

// ---------- exclusive scan of 8 counts ----------
__global__ void moe_offsets(const int* __restrict__ counts,
                            int* __restrict__ offs, int* __restrict__ fill)
{
  if (threadIdx.x == 0) {
    int s = 0;
    for (int e = 0; e < NEXP; ++e) { offs[e] = s; fill[e] = s; s += counts[e]; }
    offs[NEXP] = s;
  }
}

// ---------- scatter (token, prob) into expert buckets ----------
__global__ __launch_bounds__(256) void moe_scatter(
    const int* __restrict__ top_idx, const float* __restrict__ top_p,
    int* fill, int* __restrict__ tok_s, float* __restrict__ prb_s)
{
  const int n = blockIdx.x * 256 + threadIdx.x;
  #pragma unroll
  for (int k = 0; k < 2; ++k) {
    const int e = top_idx[n * 2 + k];
    const int pos = atomicAdd(&fill[e], 1);
    tok_s[pos] = n;
    prb_s[pos] = top_p[n * 2 + k];
  }
}

// ---------- mega: persistent producer-consumer grouped GEMM ----------
// 512 blocks (= exactly 2/CU by 72KB LDS + (512,4) reg cap) -> ALL co-resident.
// Item queue: [1280 G0 items][1280 G1 items], block b does wid = b, b+512, ...
// (5 rounds exactly). G0 item: H[s,:] = f16(relu(Xg@WfcT^T)^2); publishes
// done0[e] (dead items publish too). G1 item of expert e gates on
// done0[e]==160 (acquire), then out[tok,:] += prb * (H@WpjT^T) via atomics.
// Liveness needs NO dispatch-order assumption: all blocks resident, G0 items
// never wait -> gated blocks' predecessors are actively executing.
// Inner loop = R8's best-measured body verbatim (BK=32, 3-buf, vmcnt(6),
// line-paired zero-conflict LDS, n-tile-XCD pinning via nt=item&7).
__global__ __launch_bounds__(512, 4) void moe_mega(
    const u16* __restrict__ xh, const u16* __restrict__ wfcT,
    const u16* __restrict__ wpjT, const int* __restrict__ tok_s,
    const float* __restrict__ prb_s, const int* __restrict__ offs,
    int* __restrict__ done0, u16* __restrict__ h, float* __restrict__ out)
{
  __shared__ u16 As[3][128 * 32];   // 8 KB x3
  __shared__ u16 Bs[3][256 * 32];   // 16 KB x3  -> 72 KB total

  const int t    = threadIdx.x;
  const int lane = t & 63, wv = t >> 6;       // 8 waves
  const int wm = wv >> 2, wn = wv & 3;        // wave-tile 64x64

  // ---- item-independent lane constants ----
  const int l     = lane;
  const int kchnk = (l & 3) ^ ((l >> 3) & 3);
  const int kelem = kchnk * 8;
  const int rloc  = 2 * (l >> 3) + ((l >> 2) & 1);
  const int rsel     = lane & 15;
  const int g        = lane >> 4;
  const int halfline = rsel >> 1;
  const int slotx    = (((rsel & 1) * 4) + (g ^ (halfline & 3))) * 8;
  const int crow = g * 4;
  const int ccol = rsel;

  #pragma unroll 1
  for (int wid = blockIdx.x; wid < 2 * ITEMS_PER_MODE; wid += 512) {
    const int mode  = (wid >= ITEMS_PER_MODE);
    const int i     = mode ? wid - ITEMS_PER_MODE : wid;
    const int nt    = i & 7;                  // n-tile -> XCD pin
    const int rest  = i >> 3;
    const int e     = rest / MT;              // e slowest -> expert pipelining
    const int mtile = rest % MT;
    const int off0  = offs[e];
    const int Me    = offs[e + 1] - off0;
    const int m0    = mtile * 128;
    const bool alive = (m0 < Me);

    if (mode == 1 && alive) {                 // gate on producer completion
      if (t == 0) {
        while (__hip_atomic_load(&done0[e], __ATOMIC_ACQUIRE,
                                 __HIP_MEMORY_SCOPE_AGENT) < EXPECTED_PER_E)
          __builtin_amdgcn_s_sleep(2);
      }
    }
    __syncthreads();                          // gate broadcast + LDS item fence

    if (alive) {
      const int n0 = nt * 256;
      const u16* We = (mode ? wpjT : wfcT) + (size_t)e * CDIM * CDIM;
      const u16* Am = mode ? h : xh;

      const int rA  = wv * 16 + rloc;
      const int mrA = m0 + rA;
      const int rrA = (mrA < Me) ? mrA : (Me - 1);
      const int gaA = mode ? (off0 + rrA) : tok_s[off0 + rrA];
      const u16* asrc = Am + (size_t)gaA * CDIM + kelem;
      const int rB0 = wv * 32 + rloc;
      const int rB1 = wv * 32 + 16 + rloc;
      const u16* bsrc0 = We + (size_t)(n0 + rB0) * CDIM + kelem;
      const u16* bsrc1 = We + (size_t)(n0 + rB1) * CDIM + kelem;

      #define STAGE(T_, bb_)                                                   \
        { const int kk_ = (T_) * 32;                                           \
          __builtin_amdgcn_global_load_lds(                                    \
              (const GLOBAL_AS void*)(asrc + kk_),                             \
              (LDS_AS void*)&As[bb_][wv * 512], 16, 0, 0);                     \
          __builtin_amdgcn_global_load_lds(                                    \
              (const GLOBAL_AS void*)(bsrc0 + kk_),                            \
              (LDS_AS void*)&Bs[bb_][wv * 1024], 16, 0, 0);                    \
          __builtin_amdgcn_global_load_lds(                                    \
              (const GLOBAL_AS void*)(bsrc1 + kk_),                            \
              (LDS_AS void*)&Bs[bb_][wv * 1024 + 512], 16, 0, 0); }

      f32x4 acc[4][4] = {};

      #define COMPUTE(bb)                                                      \
        { f16x8 bv[4];                                                         \
          _Pragma("unroll")                                                    \
          for (int fn = 0; fn < 4; ++fn)                                       \
            bv[fn] = *(const f16x8*)&Bs[bb][(wn * 32 + fn * 8 + halfline) * 64 + slotx]; \
          _Pragma("unroll")                                                    \
          for (int fi = 0; fi < 4; ++fi) {                                     \
            const f16x8 av = *(const f16x8*)&As[bb][(wm * 32 + fi * 8 + halfline) * 64 + slotx]; \
            _Pragma("unroll")                                                  \
            for (int fn = 0; fn < 4; ++fn)                                     \
              acc[fi][fn] = __builtin_amdgcn_mfma_f32_16x16x32_f16(            \
                  av, bv[fn], acc[fi][fn], 0, 0, 0);                           \
          } }

      STAGE(0, 0); STAGE(1, 1); STAGE(2, 2);
      int bb = 0;
      #pragma unroll 3
      for (int T = 0; T < 64; ++T) {
        if (T < 62)       { asm volatile("s_waitcnt vmcnt(6)" ::: "memory"); }
        else if (T == 62) { asm volatile("s_waitcnt vmcnt(3)" ::: "memory"); }
        else              { asm volatile("s_waitcnt vmcnt(0)" ::: "memory"); }
        __builtin_amdgcn_s_barrier();
        COMPUTE(bb);
        __builtin_amdgcn_s_barrier();
        if (T < 61) STAGE(T + 3, bb);
        bb = (bb == 2) ? 0 : bb + 1;
      }
      #undef STAGE
      #undef COMPUTE

      // Epilogue. C/D map: col = lane&15, row = (lane>>4)*4 + j.
      if (mode == 0) {
        #pragma unroll
        for (int fi = 0; fi < 4; ++fi) {
          #pragma unroll
          for (int j = 0; j < 4; ++j) {
            const int r = m0 + wm * 64 + fi * 16 + crow + j;
            if (r >= Me) continue;
            u16* hr = h + (size_t)(off0 + r) * CDIM;
            #pragma unroll
            for (int fn = 0; fn < 4; ++fn) {
              float v = acc[fi][fn][j];
              v = v > 0.f ? v * v : 0.f;              // relu^2 fused
              hr[n0 + wn * 64 + fn * 16 + ccol] = f2h_bits(v);
            }
          }
        }
        __syncthreads();                              // all stores drained (vmcnt0 @ barrier)
        if (t == 0) { __threadfence(); atomicAdd(&done0[e], 1); }
      } else {
        #pragma unroll
        for (int fi = 0; fi < 4; ++fi) {
          #pragma unroll
          for (int j = 0; j < 4; ++j) {
            const int r = m0 + wm * 64 + fi * 16 + crow + j;
            if (r >= Me) continue;
            const int s = off0 + r;
            const float p = prb_s[s];
            float* orow = out + (size_t)tok_s[s] * CDIM;
            #pragma unroll
            for (int fn = 0; fn < 4; ++fn)
              atomicAdd(&orow[n0 + wn * 64 + fn * 16 + ccol], p * acc[fi][fn][j]);
          }
        }
      }
    } else if (mode == 0) {
      if (t == 0) atomicAdd(&done0[e], 1);            // dead G0 still publishes
    }
  }
}

extern "C" void kernel_launch(void* const* d_in, const int* in_sizes, int n_in,
                              void* d_out, int out_size, void* d_ws, size_t ws_size,
                              hipStream_t stream)
{
  const float* x   = (const float*)d_in[0];
  const float* wr  = (const float*)d_in[1];
  const float* wfc = (const float*)d_in[2];
  const float* wpj = (const float*)d_in[3];
  float* out = (float*)d_out;
  char* ws = (char*)d_ws;

  const size_t OFF_TIDX = 256;
  const size_t OFF_TP   = OFF_TIDX + (size_t)NASS * 4;
  const size_t OFF_TOK  = OFF_TP   + (size_t)NASS * 4;
  const size_t OFF_PRB  = OFF_TOK  + (size_t)NASS * 4;
  const size_t OFF_WRT  = OFF_PRB  + (size_t)NASS * 4;          // 64 KB f32
  const size_t OFF_XH   = (size_t)1 << 20;
  const size_t OFF_WFCT = OFF_XH   + (size_t)NTOK * CDIM * 2;
  const size_t OFF_WPJT = OFF_WFCT + (size_t)NEXP * CDIM * CDIM * 2;
  const size_t OFF_H    = OFF_WPJT + (size_t)NEXP * CDIM * CDIM * 2;
  const size_t NEED     = OFF_H    + (size_t)NASS * CDIM * 2;   // ~236 MB

  if (ws_size < NEED) {            // signal: absmax == |ref|max means ws too small
    hipMemsetAsync(d_out, 0, (size_t)out_size * 4, stream);
    return;
  }

  int*   counts = (int*)(ws + 0);
  int*   offs   = (int*)(ws + 64);
  int*   fill   = (int*)(ws + 128);
  int*   done0  = (int*)(ws + 192);
  int*   tidx   = (int*)(ws + OFF_TIDX);
  float* tp     = (float*)(ws + OFF_TP);
  int*   tok    = (int*)(ws + OFF_TOK);
  float* prb    = (float*)(ws + OFF_PRB);
  float* wrT    = (float*)(ws + OFF_WRT);
  u16*   xh     = (u16*)(ws + OFF_XH);
  u16*   wfcT   = (u16*)(ws + OFF_WFCT);
  u16*   wpjT   = (u16*)(ws + OFF_WPJT);
  u16*   h      = (u16*)(ws + OFF_H);

  hipMemsetAsync(ws, 0, 256, stream);                       // counts/fill/done0
  hipMemsetAsync(d_out, 0, (size_t)out_size * 4, stream);   // atomic target

  moe_wrt     <<<64, 256, 0, stream>>>(wr, wrT);
  moe_prep    <<<256 + 8192, 256, 0, stream>>>(x, wrT, xh, tidx, tp, counts,
                                               wfc, wpj, wfcT, wpjT);
  moe_offsets <<<1, 64, 0, stream>>>(counts, offs, fill);
  moe_scatter <<<NTOK / 256, 256, 0, stream>>>(tidx, tp, fill, tok, prb);
  moe_mega    <<<512, 512, 0, stream>>>(xh, wfcT, wpjT, tok, prb, offs,
                                        done0, h, out);
}

// Round 12
// 614.924 us; speedup vs baseline: 1.1224x; 1.1224x over previous
//
#include <hip/hip_runtime.h>

typedef float   f32x4 __attribute__((ext_vector_type(4)));
typedef _Float16 f16x8 __attribute__((ext_vector_type(8)));
typedef short   s16x8 __attribute__((ext_vector_type(8)));
typedef short   s16x4 __attribute__((ext_vector_type(4)));
typedef unsigned short u16;

#define NTOK 8192
#define CDIM 2048
#define NEXP 8
#define NASS 16384   // NTOK * TOP_K
#define MTILES 24    // BM=128 slack: supports Me up to 3072

#define GLOBAL_AS __attribute__((address_space(1)))
#define LDS_AS    __attribute__((address_space(3)))

__device__ __forceinline__ u16 f2h_bits(float f) {
  _Float16 h = (_Float16)f;
  union { _Float16 h; u16 u; } v;
  v.h = h;
  return v.u;
}

// ---------- tiny: wr [C][E] f32 -> wrT [E][C] f32 (coalesced router reads) ----------
__global__ __launch_bounds__(256) void moe_wrt(
    const float* __restrict__ wr, float* __restrict__ wrT)
{
  const int gid = blockIdx.x * 256 + threadIdx.x;   // 16384 elems
  const int c = gid >> 3, e = gid & 7;
  wrT[e * CDIM + c] = wr[c * NEXP + e];
}

// ---------- router: grid-stride, LDS count reduce (8 atomics/block) ----------
__global__ __launch_bounds__(256) void moe_router(
    const float* __restrict__ x, const float* __restrict__ wrT,
    u16* __restrict__ xh, int* __restrict__ top_idx,
    float* __restrict__ top_p, int* __restrict__ counts)
{
  __shared__ int scnt[NEXP];
  if (threadIdx.x < NEXP) scnt[threadIdx.x] = 0;
  __syncthreads();
  const int wave = threadIdx.x >> 6, lane = threadIdx.x & 63;
  for (int i = 0; i < 8; ++i) {                   // 32 tokens per block
    const int n = blockIdx.x * 32 + i * 4 + wave;
    const float* xr = x + (size_t)n * CDIM;
    u16* xhr = xh + (size_t)n * CDIM;
    float acc[NEXP] = {};
    #pragma unroll
    for (int ii = 0; ii < CDIM / 256; ++ii) {
      const int c = ii * 256 + lane * 4;
      const f32x4 xv = *(const f32x4*)(xr + c);
      s16x4 hv;
      #pragma unroll
      for (int j = 0; j < 4; ++j) hv[j] = (short)f2h_bits(xv[j]);
      *(s16x4*)(xhr + c) = hv;                    // fused x -> f16 (8B store)
      #pragma unroll
      for (int e = 0; e < NEXP; ++e) {            // coalesced f32x4 per expert row
        const f32x4 wv = *(const f32x4*)(wrT + (size_t)e * CDIM + c);
        acc[e] += xv[0]*wv[0] + xv[1]*wv[1] + xv[2]*wv[2] + xv[3]*wv[3];
      }
    }
    #pragma unroll
    for (int off = 32; off > 0; off >>= 1) {
      #pragma unroll
      for (int e = 0; e < NEXP; ++e) acc[e] += __shfl_xor(acc[e], off);
    }
    if (lane == 0) {
      int i0 = 0; float v0 = acc[0];
      #pragma unroll
      for (int e = 1; e < NEXP; ++e) { if (acc[e] > v0) { v0 = acc[e]; i0 = e; } }
      int i1 = -1; float v1 = -3.4e38f;
      #pragma unroll
      for (int e = 0; e < NEXP; ++e) { if (e != i0 && acc[e] > v1) { v1 = acc[e]; i1 = e; } }
      const float ex = __expf(v1 - v0);           // softmax over the 2 kept logits
      const float p0 = 1.f / (1.f + ex);
      top_idx[n * 2 + 0] = i0; top_idx[n * 2 + 1] = i1;
      top_p[n * 2 + 0] = p0;   top_p[n * 2 + 1] = 1.f - p0;
      atomicAdd(&scnt[i0], 1);                    // LDS atomics (cheap)
      atomicAdd(&scnt[i1], 1);
    }
  }
  __syncthreads();
  if (threadIdx.x < NEXP) atomicAdd(&counts[threadIdx.x], scnt[threadIdx.x]);
}

// ---------- exclusive scan of 8 counts ----------
__global__ void moe_offsets(const int* __restrict__ counts,
                            int* __restrict__ offs, int* __restrict__ fill)
{
  if (threadIdx.x == 0) {
    int s = 0;
    for (int e = 0; e < NEXP; ++e) { offs[e] = s; fill[e] = s; s += counts[e]; }
    offs[NEXP] = s;
  }
}

// ---------- scatter (token, prob) into expert buckets ----------
__global__ __launch_bounds__(256) void moe_scatter(
    const int* __restrict__ top_idx, const float* __restrict__ top_p,
    int* fill, int* __restrict__ tok_s, float* __restrict__ prb_s)
{
  const int n = blockIdx.x * 256 + threadIdx.x;
  #pragma unroll
  for (int k = 0; k < 2; ++k) {
    const int e = top_idx[n * 2 + k];
    const int pos = atomicAdd(&fill[e], 1);
    tok_s[pos] = n;
    prb_s[pos] = top_p[n * 2 + k];
  }
}

// ---------- transpose+convert: w [E][K][N] fp32 -> wT [E][N][K] f16 ----------
// 64 K-rows x 128 N-cols per block (R9-measured good).
__global__ __launch_bounds__(256) void moe_transpose(
    const float* __restrict__ wfc, const float* __restrict__ wpj,
    u16* __restrict__ wfcT, u16* __restrict__ wpjT)
{
  const float* src = blockIdx.z ? wpj : wfc;
  u16* dst = blockIdx.z ? wpjT : wfcT;
  const int e = blockIdx.y;
  src += (size_t)e * CDIM * CDIM;
  dst += (size_t)e * CDIM * CDIM;
  const int tr = (blockIdx.x >> 4) * 64;    // src row (K) base, 32 tiles
  const int tc = (blockIdx.x & 15) * 128;   // src col (N) base, 16 tiles
  __shared__ float lds[64][129];            // +1 pad breaks bank conflicts
  const int t = threadIdx.x;
  #pragma unroll
  for (int p = 0; p < 8; ++p) {
    const int r  = p * 8 + (t >> 5);
    const int c4 = (t & 31) * 4;
    const f32x4 v = *(const f32x4*)(src + (size_t)(tr + r) * CDIM + tc + c4);
    #pragma unroll
    for (int j = 0; j < 4; ++j) lds[r][c4 + j] = v[j];
  }
  __syncthreads();
  const int d  = t >> 1;                    // out row (N-local), 0..127
  const int ks = (t & 1) * 32;              // K base this thread writes
  u16* drow = dst + (size_t)(tc + d) * CDIM + tr + ks;
  #pragma unroll
  for (int q = 0; q < 4; ++q) {
    s16x8 o;
    #pragma unroll
    for (int j = 0; j < 8; ++j) o[j] = (short)f2h_bits(lds[ks + q * 8 + j][d]);
    *(s16x8*)(drow + q * 8) = o;
  }
}

// ---------- grouped GEMM: R8's best-measured body (242 us), verbatim ----------
// 128x256 tile, BK=32, 3-buffer depth-2 prefetch, DOUBLE barrier per tile
// (R9's single-barrier variant measured +8 us/GEMM -> reverted).
// Ledger (3 loads/wave/tile): prologue {0,1,2}=9; iter T: vmcnt(6) retires
// tile T (leaves {T+1,T+2}); barrier; COMPUTE(bufT); barrier; STAGE(T+3->bufT).
// n-tile-per-XCD dispatch (id&7 = nt): perfect balance (R8: 277->242).
// LDS line-paired layout (measured 0 conflicts R4/R6/R8/R9):
//   phys(r,c) = line (r>>1), slot (r&1)*4 + (c ^ ((r>>1)&3))
// MODE 0: H[s,:] = f16(relu(Xg @ WfcT^T)^2)   (A = xh gathered via tok_s)
// MODE 1: out[tok,:] += prb * (H @ WpjT^T)    (A = h linear; atomic combine)
template<int MODE>
__global__ __launch_bounds__(512, 4) void moe_gemm12(
    const u16* __restrict__ A, const u16* __restrict__ W,
    const int* __restrict__ tok_s, const float* __restrict__ prb_s,
    const int* __restrict__ offs, u16* __restrict__ hout,
    float* __restrict__ out)
{
  const int id    = blockIdx.x;
  const int nt    = id & 7;                   // n-tile -> XCD (balance + B locality)
  const int rid   = id >> 3;                  // e-major: rid = e*MTILES + mtile
  const int e     = rid / MTILES;
  const int mtile = rid % MTILES;
  const int off0  = offs[e];
  const int Me    = offs[e + 1] - off0;
  const int m0    = mtile * 128;
  if (m0 >= Me) return;
  const int n0 = nt * 256;
  const u16* We = W + (size_t)e * CDIM * CDIM;

  __shared__ u16 As[3][128 * 32];   // 8 KB x3
  __shared__ u16 Bs[3][256 * 32];   // 16 KB x3  -> 72 KB total

  const int t    = threadIdx.x;
  const int lane = t & 63, wv = t >> 6;       // 8 waves
  const int wm = wv >> 2, wn = wv & 3;        // wave-tile: rows wm*64, cols wn*64

  // ---- staging precompute (per lane) ----
  const int l     = lane;
  const int kchnk = (l & 3) ^ ((l >> 3) & 3); // source k-chunk for linear LDS fill
  const int kelem = kchnk * 8;
  const int rloc  = 2 * (l >> 3) + ((l >> 2) & 1);   // row within 16-row instr block
  const int rA  = wv * 16 + rloc;
  const int mrA = m0 + rA;
  const int rrA = (mrA < Me) ? mrA : (Me - 1);       // clamp tail (dup, benign)
  const int gaA = (MODE == 0) ? tok_s[off0 + rrA] : (off0 + rrA);
  const u16* asrc = A + (size_t)gaA * CDIM + kelem;
  const int rB0 = wv * 32 + rloc;
  const int rB1 = wv * 32 + 16 + rloc;
  const u16* bsrc0 = We + (size_t)(n0 + rB0) * CDIM + kelem;
  const u16* bsrc1 = We + (size_t)(n0 + rB1) * CDIM + kelem;

  #define STAGE(T_, bb_)                                                       \
    { const int kk_ = (T_) * 32;                                               \
      __builtin_amdgcn_global_load_lds(                                        \
          (const GLOBAL_AS void*)(asrc + kk_),                                 \
          (LDS_AS void*)&As[bb_][wv * 512], 16, 0, 0);                         \
      __builtin_amdgcn_global_load_lds(                                        \
          (const GLOBAL_AS void*)(bsrc0 + kk_),                                \
          (LDS_AS void*)&Bs[bb_][wv * 1024], 16, 0, 0);                        \
      __builtin_amdgcn_global_load_lds(                                        \
          (const GLOBAL_AS void*)(bsrc1 + kk_),                                \
          (LDS_AS void*)&Bs[bb_][wv * 1024 + 512], 16, 0, 0); }

  // ---- read addressing (per lane) ----
  const int rsel     = lane & 15;
  const int g        = lane >> 4;
  const int halfline = rsel >> 1;
  const int slotx    = (((rsel & 1) * 4) + (g ^ (halfline & 3))) * 8;  // u16 units

  f32x4 acc[4][4] = {};

  #define COMPUTE(bb)                                                          \
    { f16x8 bv[4];                                                             \
      _Pragma("unroll")                                                        \
      for (int fn = 0; fn < 4; ++fn)                                           \
        bv[fn] = *(const f16x8*)&Bs[bb][(wn * 32 + fn * 8 + halfline) * 64 + slotx]; \
      _Pragma("unroll")                                                        \
      for (int fi = 0; fi < 4; ++fi) {                                         \
        const f16x8 av = *(const f16x8*)&As[bb][(wm * 32 + fi * 8 + halfline) * 64 + slotx]; \
        _Pragma("unroll")                                                      \
        for (int fn = 0; fn < 4; ++fn)                                         \
          acc[fi][fn] = __builtin_amdgcn_mfma_f32_16x16x32_f16(                \
              av, bv[fn], acc[fi][fn], 0, 0, 0);                               \
      } }

  STAGE(0, 0); STAGE(1, 1); STAGE(2, 2);        // 9 in flight
  int bb = 0;
  #pragma unroll 3
  for (int T = 0; T < 64; ++T) {
    if (T < 62)       { asm volatile("s_waitcnt vmcnt(6)" ::: "memory"); }
    else if (T == 62) { asm volatile("s_waitcnt vmcnt(3)" ::: "memory"); }
    else              { asm volatile("s_waitcnt vmcnt(0)" ::: "memory"); }
    __builtin_amdgcn_s_barrier();               // all waves' tile-T loads landed
    COMPUTE(bb);
    __builtin_amdgcn_s_barrier();               // reads done before re-staging buf
    if (T < 61) STAGE(T + 3, bb);               // (T+3)%3 == T%3 == bb
    bb = (bb == 2) ? 0 : bb + 1;
  }
  #undef STAGE
  #undef COMPUTE

  // Epilogue. C/D map: col = lane&15, row = (lane>>4)*4 + j.
  const int crow = g * 4;
  const int ccol = rsel;
  #pragma unroll
  for (int fi = 0; fi < 4; ++fi) {
    #pragma unroll
    for (int j = 0; j < 4; ++j) {
      const int r = m0 + wm * 64 + fi * 16 + crow + j;
      if (r >= Me) continue;
      const int s = off0 + r;
      if (MODE == 0) {
        u16* hr = hout + (size_t)s * CDIM;
        #pragma unroll
        for (int fn = 0; fn < 4; ++fn) {
          float v = acc[fi][fn][j];
          v = v > 0.f ? v * v : 0.f;                  // relu^2 fused
          hr[n0 + wn * 64 + fn * 16 + ccol] = f2h_bits(v);
        }
      } else {
        const float p = prb_s[s];
        float* orow = out + (size_t)tok_s[s] * CDIM;
        #pragma unroll
        for (int fn = 0; fn < 4; ++fn)
          atomicAdd(&orow[n0 + wn * 64 + fn * 16 + ccol], p * acc[fi][fn][j]);
      }
    }
  }
}

extern "C" void kernel_launch(void* const* d_in, const int* in_sizes, int n_in,
                              void* d_out, int out_size, void* d_ws, size_t ws_size,
                              hipStream_t stream)
{
  const float* x   = (const float*)d_in[0];
  const float* wr  = (const float*)d_in[1];
  const float* wfc = (const float*)d_in[2];
  const float* wpj = (const float*)d_in[3];
  float* out = (float*)d_out;
  char* ws = (char*)d_ws;

  const size_t OFF_TIDX = 256;
  const size_t OFF_TP   = OFF_TIDX + (size_t)NASS * 4;
  const size_t OFF_TOK  = OFF_TP   + (size_t)NASS * 4;
  const size_t OFF_PRB  = OFF_TOK  + (size_t)NASS * 4;
  const size_t OFF_WRT  = OFF_PRB  + (size_t)NASS * 4;          // 64 KB f32
  const size_t OFF_XH   = (size_t)1 << 20;
  const size_t OFF_WFCT = OFF_XH   + (size_t)NTOK * CDIM * 2;
  const size_t OFF_WPJT = OFF_WFCT + (size_t)NEXP * CDIM * CDIM * 2;
  const size_t OFF_H    = OFF_WPJT + (size_t)NEXP * CDIM * CDIM * 2;
  const size_t NEED     = OFF_H    + (size_t)NASS * CDIM * 2;   // ~236 MB

  if (ws_size < NEED) {            // signal: absmax == |ref|max means ws too small
    hipMemsetAsync(d_out, 0, (size_t)out_size * 4, stream);
    return;
  }

  int*   counts = (int*)(ws + 0);
  int*   offs   = (int*)(ws + 64);
  int*   fill   = (int*)(ws + 128);
  int*   tidx   = (int*)(ws + OFF_TIDX);
  float* tp     = (float*)(ws + OFF_TP);
  int*   tok    = (int*)(ws + OFF_TOK);
  float* prb    = (float*)(ws + OFF_PRB);
  float* wrT    = (float*)(ws + OFF_WRT);
  u16*   xh     = (u16*)(ws + OFF_XH);
  u16*   wfcT   = (u16*)(ws + OFF_WFCT);
  u16*   wpjT   = (u16*)(ws + OFF_WPJT);
  u16*   h      = (u16*)(ws + OFF_H);

  hipMemsetAsync(ws, 0, 256, stream);                       // counts/fill
  hipMemsetAsync(d_out, 0, (size_t)out_size * 4, stream);   // atomic target

  moe_wrt     <<<64, 256, 0, stream>>>(wr, wrT);
  moe_router  <<<256, 256, 0, stream>>>(x, wrT, xh, tidx, tp, counts);
  moe_offsets <<<1, 64, 0, stream>>>(counts, offs, fill);
  moe_scatter <<<NTOK / 256, 256, 0, stream>>>(tidx, tp, fill, tok, prb);
  moe_transpose<<<dim3(512, NEXP, 2), 256, 0, stream>>>(wfc, wpj, wfcT, wpjT);
  moe_gemm12<0><<<NEXP * 8 * MTILES, 512, 0, stream>>>(xh, wfcT, tok, nullptr, offs, h, nullptr);
  moe_gemm12<1><<<NEXP * 8 * MTILES, 512, 0, stream>>>(h,  wpjT, tok, prb,     offs, nullptr, out);
}